// Round 2
// baseline (240.751 us; speedup 1.0000x reference)
//
#include <hip/hip_runtime.h>
#include <hip/hip_bf16.h>
#include <stdint.h>

#define NN 8192
#define FIN 512
#define HID 256

typedef short bf16x8 __attribute__((ext_vector_type(8)));
typedef float f32x4 __attribute__((ext_vector_type(4)));

__device__ __forceinline__ uint32_t pk2(float lo, float hi) {
  uint32_t a = __float_as_uint(lo), b = __float_as_uint(hi);
  a = (a + 0x7FFFu + ((a >> 16) & 1u)) >> 16;
  b = (b + 0x7FFFu + ((b >> 16) & 1u)) >> 16;
  return a | (b << 16);
}

// workspace byte offsets
#define OFF_SEQB   0u         // 8192*512*2  = 8388608
#define OFF_WTB    8388608u   // 256*512*2   = 262144
#define OFF_FTST   8650752u   // 256*8192*2  = 4194304
#define OFF_F1     12845056u  // 8192*4
#define OFF_F2     12877824u  // 8192*4
#define OFF_Z      12910592u  // 8192*4
#define OFF_F2MAX  12943360u  // 4

// ---- seq f32 -> bf16 ----
__global__ void k_cvt_seq(const float* __restrict__ seq, short* __restrict__ seqb) {
  int i = (blockIdx.x * 256 + threadIdx.x) * 4;
  float4 v = *(const float4*)(seq + i);
  uint2 o; o.x = pk2(v.x, v.y); o.y = pk2(v.z, v.w);
  *(uint2*)(seqb + i) = o;
}

// ---- W[512,256] -> WT bf16 [256,512] ----
__global__ void k_wt(const float* __restrict__ W, short* __restrict__ WTb) {
  int h = blockIdx.x;   // 0..255
  int t = threadIdx.x;  // 0..255
  int k = t * 2;
  float w0 = W[k * 256 + h], w1 = W[(k + 1) * 256 + h];
  ((uint32_t*)(WTb + h * 512))[t] = pk2(w0, w1);
}

// ---- projection GEMM: fts = seq@W (bf16 MFMA); epilogue: ftsT, f1, f2, f2max ----
__global__ __launch_bounds__(256) void k_proj(
    const short* __restrict__ seqb, const short* __restrict__ WTb,
    const float* __restrict__ a1, const float* __restrict__ b1,
    const float* __restrict__ a2, const float* __restrict__ b2,
    short* __restrict__ ftsT, float* __restrict__ f1g, float* __restrict__ f2g,
    uint32_t* __restrict__ f2maxenc) {
  __shared__ short At[64][72];  // 144B rows: 16B-aligned, ~2-way banks
  __shared__ float f1a[64], f2a[64];
  const int t = threadIdx.x;
  const int l = t & 63, w = t >> 6;  // wn = w
  const int lr = l & 15, lg = l >> 4;
  const int R0 = blockIdx.x * 64;
  const int srow = t >> 2, scol = (t & 3) * 16;
  f32x4 acc[4][4] = {};
  if (t < 64) { f1a[t] = 0.f; f2a[t] = 0.f; }
  for (int kt = 0; kt < FIN; kt += 64) {
    uint4 s0 = *(const uint4*)(seqb + (size_t)(R0 + srow) * FIN + kt + scol);
    uint4 s1 = *(const uint4*)(seqb + (size_t)(R0 + srow) * FIN + kt + scol + 8);
    __syncthreads();
    *(uint4*)&At[srow][scol] = s0;
    *(uint4*)&At[srow][scol + 8] = s1;
    __syncthreads();
#pragma unroll
    for (int kk = 0; kk < 2; ++kk) {
      bf16x8 af[4];
#pragma unroll
      for (int mf = 0; mf < 4; ++mf)
        af[mf] = *(const bf16x8*)&At[mf * 16 + lr][kk * 32 + lg * 8];
#pragma unroll
      for (int nf = 0; nf < 4; ++nf) {
        int h = w * 64 + nf * 16 + lr;
        bf16x8 bfr = *(const bf16x8*)(WTb + h * FIN + kt + kk * 32 + lg * 8);
#pragma unroll
        for (int mf = 0; mf < 4; ++mf)
          acc[mf][nf] = __builtin_amdgcn_mfma_f32_16x16x32_bf16(af[mf], bfr, acc[mf][nf], 0, 0, 0);
      }
    }
  }
  __syncthreads();
  float a1v[4], a2v[4];
#pragma unroll
  for (int nf = 0; nf < 4; ++nf) {
    int h = w * 64 + nf * 16 + lr;
    a1v[nf] = a1[h]; a2v[nf] = a2[h];
  }
#pragma unroll
  for (int mf = 0; mf < 4; ++mf) {
#pragma unroll
    for (int nf = 0; nf < 4; ++nf) {  // ftsT[h][i] bf16 store
      int h = w * 64 + nf * 16 + lr;
      int r0 = R0 + mf * 16 + lg * 4;
      uint2 o; o.x = pk2(acc[mf][nf][0], acc[mf][nf][1]);
      o.y = pk2(acc[mf][nf][2], acc[mf][nf][3]);
      *(uint2*)(ftsT + (size_t)h * NN + r0) = o;
    }
#pragma unroll
    for (int e = 0; e < 4; ++e) {  // f1/f2 row dots from fp32 acc
      float p1 = 0.f, p2 = 0.f;
#pragma unroll
      for (int nf = 0; nf < 4; ++nf) { p1 += acc[mf][nf][e] * a1v[nf]; p2 += acc[mf][nf][e] * a2v[nf]; }
#pragma unroll
      for (int m = 8; m >= 1; m >>= 1) { p1 += __shfl_xor(p1, m, 16); p2 += __shfl_xor(p2, m, 16); }
      if (lr == 0) {
        atomicAdd(&f1a[mf * 16 + lg * 4 + e], p1);
        atomicAdd(&f2a[mf * 16 + lg * 4 + e], p2);
      }
    }
  }
  __syncthreads();
  if (t < 64) {
    float v1 = f1a[t] + b1[0];
    float v2 = f2a[t] + b2[0];
    f1g[R0 + t] = v1; f2g[R0 + t] = v2;
    uint32_t u = __float_as_uint(v2);
    u = (u & 0x80000000u) ? ~u : (u | 0x80000000u);  // order-preserving encode
    atomicMax(f2maxenc, u);
  }
}

// ---- fused scores->softmax-numerator->PV (flash, no rescale thanks to m=lrelu(f1+f2max)) ----
__global__ __launch_bounds__(512) void k_flash(
    const float* __restrict__ bias, const short* __restrict__ ftsT,
    const float* __restrict__ f1g, const float* __restrict__ f2g,
    const uint32_t* __restrict__ f2maxenc,
    float* __restrict__ outacc, float* __restrict__ Zg) {
  __shared__ short Et[128][72];
  const int t = threadIdx.x;
  const int l = t & 63, wid = t >> 6;
  const int wm = wid >> 2, wn = wid & 3;
  const int lr = l & 15, lg = l >> 4;
  const int R0 = blockIdx.x * 128;
  const int jbase = blockIdx.y * 1024;
  const int erow = t >> 4;        // 0..31
  const int ecol = (t & 15) * 4;  // 0..60
  uint32_t ue = *f2maxenc;
  float f2mx = __uint_as_float((ue & 0x80000000u) ? (ue ^ 0x80000000u) : ~ue);
  float f1r[4], mr[4];
#pragma unroll
  for (int k = 0; k < 4; ++k) {
    float v = f1g[R0 + k * 32 + erow];
    f1r[k] = v;
    float x = v + f2mx;
    mr[k] = fmaxf(x, 0.2f * x);  // lrelu, exact row-max bound (bias<=0)
  }
  f32x4 acc[4][4] = {};
  float z[4] = {0.f, 0.f, 0.f, 0.f};
  float4 bb[4], f2v;
  f2v = *(const float4*)(f2g + jbase + ecol);
#pragma unroll
  for (int k = 0; k < 4; ++k)
    bb[k] = *(const float4*)(bias + (size_t)(R0 + k * 32 + erow) * NN + jbase + ecol);
  const int NT = 16;  // 1024/64 tiles per j-chunk
  for (int jt = 0; jt < NT; ++jt) {
    const int jcur = jbase + jt * 64;
    const int jn = (jt + 1 < NT) ? (jcur + 64) : jbase;  // clamp: last prefetch unused
    float4 bn[4], f2n;
    f2n = *(const float4*)(f2g + jn + ecol);
#pragma unroll
    for (int k = 0; k < 4; ++k)
      bn[k] = *(const float4*)(bias + (size_t)(R0 + k * 32 + erow) * NN + jn + ecol);
    // E tile: p = exp(lrelu(f1+f2)+bias - m), fp32; Z in fp32; bf16 to LDS
#pragma unroll
    for (int k = 0; k < 4; ++k) {
      float p[4];
#pragma unroll
      for (int e = 0; e < 4; ++e) {
        float s = f1r[k] + ((const float*)&f2v)[e];
        float ls = fmaxf(s, 0.2f * s);
        float sc = ls + ((const float*)&bb[k])[e];
        p[e] = __expf(sc - mr[k]);
      }
      z[k] += (p[0] + p[1]) + (p[2] + p[3]);
      uint2 o; o.x = pk2(p[0], p[1]); o.y = pk2(p[2], p[3]);
      *(uint2*)&Et[k * 32 + erow][ecol] = o;
    }
    __syncthreads();
#pragma unroll
    for (int kk = 0; kk < 2; ++kk) {
      bf16x8 af[4];
#pragma unroll
      for (int mf = 0; mf < 4; ++mf)
        af[mf] = *(const bf16x8*)&Et[wm * 64 + mf * 16 + lr][kk * 32 + lg * 8];
#pragma unroll
      for (int nf = 0; nf < 4; ++nf) {
        int h = wn * 64 + nf * 16 + lr;
        bf16x8 bfr = *(const bf16x8*)(ftsT + (size_t)h * NN + jcur + kk * 32 + lg * 8);
#pragma unroll
        for (int mf = 0; mf < 4; ++mf)
          acc[mf][nf] = __builtin_amdgcn_mfma_f32_16x16x32_bf16(af[mf], bfr, acc[mf][nf], 0, 0, 0);
      }
    }
    __syncthreads();
#pragma unroll
    for (int k = 0; k < 4; ++k) bb[k] = bn[k];
    f2v = f2n;
  }
  // Z partials
#pragma unroll
  for (int k = 0; k < 4; ++k) {
    float zz = z[k];
#pragma unroll
    for (int m = 8; m >= 1; m >>= 1) zz += __shfl_xor(zz, m, 16);
    if ((t & 15) == 0) atomicAdd(&Zg[R0 + k * 32 + erow], zz);
  }
  // numerator partials into d_out
#pragma unroll
  for (int mf = 0; mf < 4; ++mf)
#pragma unroll
    for (int nf = 0; nf < 4; ++nf) {
      int col = wn * 64 + nf * 16 + lr;
      int row = R0 + wm * 64 + mf * 16 + lg * 4;
#pragma unroll
      for (int e = 0; e < 4; ++e)
        atomicAdd(&outacc[(size_t)(row + e) * HID + col], acc[mf][nf][e]);
    }
}

// ---- finalize: out = elu(num/Z + bias_zero) ----
__global__ void k_final(float* __restrict__ outp, const float* __restrict__ Zg,
                        const float* __restrict__ bz) {
  int i4 = (blockIdx.x * 256 + threadIdx.x) * 4;
  int row = i4 >> 8;
  int col = i4 & 255;
  float4 v = *(float4*)(outp + i4);
  float zr = 1.0f / Zg[row];
  float4 b = *(const float4*)(bz + col);
  float r[4] = {v.x * zr + b.x, v.y * zr + b.y, v.z * zr + b.z, v.w * zr + b.w};
#pragma unroll
  for (int e = 0; e < 4; ++e) r[e] = r[e] > 0.f ? r[e] : (__expf(r[e]) - 1.f);
  *(float4*)(outp + i4) = make_float4(r[0], r[1], r[2], r[3]);
}

extern "C" void kernel_launch(void* const* d_in, const int* in_sizes, int n_in,
                              void* d_out, int out_size, void* d_ws, size_t ws_size,
                              hipStream_t stream) {
  const float* seq  = (const float*)d_in[0];
  const float* bias = (const float*)d_in[1];
  const float* W    = (const float*)d_in[2];
  const float* a1   = (const float*)d_in[3];
  const float* b1   = (const float*)d_in[4];
  const float* a2   = (const float*)d_in[5];
  const float* b2   = (const float*)d_in[6];
  const float* bz   = (const float*)d_in[7];
  float* out = (float*)d_out;
  char* ws = (char*)d_ws;
  short* seqb = (short*)(ws + OFF_SEQB);
  short* WTb  = (short*)(ws + OFF_WTB);
  short* ftsT = (short*)(ws + OFF_FTST);
  float* f1g  = (float*)(ws + OFF_F1);
  float* f2g  = (float*)(ws + OFF_F2);
  float* Zg   = (float*)(ws + OFF_Z);
  uint32_t* f2m = (uint32_t*)(ws + OFF_F2MAX);

  hipMemsetAsync(d_out, 0, (size_t)NN * HID * 4, stream);
  hipMemsetAsync(Zg, 0, NN * 4, stream);
  hipMemsetAsync(f2m, 0, 4, stream);

  k_cvt_seq<<<4096, 256, 0, stream>>>(seq, seqb);
  k_wt<<<256, 256, 0, stream>>>(W, WTb);
  k_proj<<<128, 256, 0, stream>>>(seqb, WTb, a1, b1, a2, b2, ftsT, f1g, f2g, f2m);
  k_flash<<<dim3(64, 8), 512, 0, stream>>>(bias, ftsT, f1g, f2g, f2m, out, Zg);
  k_final<<<2048, 256, 0, stream>>>(out, Zg, bz);
}